// Round 1
// baseline (110.114 us; speedup 1.0000x reference)
//
#include <hip/hip_runtime.h>

#define BINS 256
#define EMB  256
#define BH   8          // 2*4 leading batch dims flattened

// out[bh][i][j][d] = (s[bh][i][d] + s[bh][j][d]) * 0.5f
//                  + s[bh][i][d] * s[bh][j][d]
//                  + T[|i-j|][d]
//
// One block per (bh, i): 256 threads, each thread owns float4 lane d4 = t&63
// and j-slot tj = t>>6; loops jb over 0..255 step 4. s_i is register-resident;
// s_j / T reads are coalesced and L2-hit; stores are contiguous float4.
__global__ __launch_bounds__(256) void outputhead_kernel(
        const float* __restrict__ seq,   // [BH][BINS][EMB]
        const float* __restrict__ tab,   // [256][EMB]
        float* __restrict__ out)         // [BH][BINS][BINS][EMB]
{
    const int blk = blockIdx.x;          // bh*256 + i
    const int bh  = blk >> 8;
    const int i   = blk & 255;
    const int t   = threadIdx.x;         // 0..255
    const int d4  = t & 63;              // float4 lane within d-dim (256/4=64)
    const int tj  = t >> 6;              // 0..3 j sub-slot

    const float4* __restrict__ seq4 = reinterpret_cast<const float4*>(seq);
    const float4* __restrict__ tab4 = reinterpret_cast<const float4*>(tab);
    float4* __restrict__ out4       = reinterpret_cast<float4*>(out);

    // invariant across the whole j loop
    const float4 si = seq4[(bh * BINS + i) * (EMB / 4) + d4];

    const size_t seq_bh_base  = (size_t)bh * BINS * (EMB / 4);
    const size_t out_row_base = ((size_t)(bh * BINS + i)) * BINS * (EMB / 4);

    #pragma unroll 4
    for (int jb = 0; jb < BINS; jb += 4) {
        const int j    = jb + tj;
        const int dist = (i > j) ? (i - j) : (j - i);   // |i-j| <= 255, clip is a no-op

        const float4 sj = seq4[seq_bh_base + (size_t)j * (EMB / 4) + d4];
        const float4 tv = tab4[(size_t)dist * (EMB / 4) + d4];

        float4 o;
        o.x = (si.x + sj.x) * 0.5f + si.x * sj.x + tv.x;
        o.y = (si.y + sj.y) * 0.5f + si.y * sj.y + tv.y;
        o.z = (si.z + sj.z) * 0.5f + si.z * sj.z + tv.z;
        o.w = (si.w + sj.w) * 0.5f + si.w * sj.w + tv.w;

        out4[out_row_base + (size_t)j * (EMB / 4) + d4] = o;
    }
}

extern "C" void kernel_launch(void* const* d_in, const int* in_sizes, int n_in,
                              void* d_out, int out_size, void* d_ws, size_t ws_size,
                              hipStream_t stream) {
    const float* seq = (const float*)d_in[0];   // (2,4,256,256) fp32
    const float* tab = (const float*)d_in[1];   // (256,256) fp32
    float* out = (float*)d_out;                 // (2,4,256,256,256) fp32

    dim3 grid(BH * BINS);   // 2048 blocks
    dim3 block(256);
    outputhead_kernel<<<grid, block, 0, stream>>>(seq, tab, out);
}